// Round 10
// baseline (127.308 us; speedup 1.0000x reference)
//
#include <hip/hip_runtime.h>
#include <hip/hip_bf16.h>
#include <math.h>

// Problem constants (N, C, H, W) = (4, 256, 64, 64), out_C = 256, FS=3, pad=1, stride=1
#define NB     4
#define CIN    256
#define HH     64
#define WW     64
#define OUTC   256
#define K2     9
#define KTOT   2304                // CIN * K2
#define HWSZ   4096                // HH * WW
#define NSTEPS 72                  // KTOT / 32
#define MTOT   16384               // NB * HWSZ

// K ordering everywhere: k' = tap*256 + c (tap-major).

typedef __attribute__((ext_vector_type(4)))  float  floatx4;
typedef __attribute__((ext_vector_type(16))) float  floatx16;
typedef __attribute__((ext_vector_type(8)))  short  short8;
typedef __attribute__((ext_vector_type(4)))  short  short4v;
typedef __attribute__((ext_vector_type(4)))  int    intx4;

__device__ __forceinline__ unsigned short f2bf(float f) {
  union { float f; unsigned u; } v; v.f = f;
  unsigned r = v.u + 0x7FFF + ((v.u >> 16) & 1);   // round-to-nearest-even
  return (unsigned short)(r >> 16);
}
__device__ __forceinline__ float b2f(unsigned short s) {
  union { unsigned u; float f; } v; v.u = ((unsigned)s) << 16;
  return v.f;
}

// Barrier that orders ONLY LDS traffic (lgkmcnt) — does NOT drain vmcnt, so
// global prefetches stay in flight across it. __syncthreads() would emit
// s_waitcnt vmcnt(0) lgkmcnt(0) and kill the pipeline (m97 stall).
__device__ __forceinline__ void barrier_lds_only() {
  asm volatile("s_waitcnt lgkmcnt(0)" ::: "memory");
  __builtin_amdgcn_s_barrier();
}

// ---------------------------------------------------------------------------
// MAIN-PATH workspace (bytes):
//   Bfrag  : [144 s16][8 nt][64 lane][8 bf16]  = 1,179,648  (32x32x16 frag order)
//   B2frag : [72 s32][2 nt][64 lane][8 bf16]   =   147,456  (16x16x32 frag order)
//   xt     : [4][64][64][256] bf16             = 8,388,608  (channel-last x)
#define WSM_BFRAG   0
#define WSM_B2FRAG  1179648
#define WSM_XT      (1179648 + 147456)
#define WSM_END     (WSM_XT + NB * HWSZ * CIN * 2)
// FALLBACK workspace (round-2 path, only if ws is tiny):
#define WSF_BW      0
#define WSF_B2W     (KTOT * OUTC * 2)
#define WSF_OM      (WSF_B2W + KTOT * 32 * 2)
#define WSF_END     (WSF_OM + NB * 27 * HWSZ * 4)

// ---------------------------------------------------------------------------
// Kernel 0 (main): xpose (blocks 0..255) + Bfrag pack (256..543) + B2frag
// pack (544..579).
// ---------------------------------------------------------------------------
__global__ __launch_bounds__(256) void prep_main_kernel(
    const float* __restrict__ dcn_w, const float* __restrict__ offw,
    const float* __restrict__ x,
    unsigned short* __restrict__ Bfrag, unsigned short* __restrict__ B2frag,
    unsigned short* __restrict__ xt) {
  int bid = blockIdx.x;
  int tid = threadIdx.x;
  if (bid < 256) {
    __shared__ unsigned short T[64 * 266];   // [w][c], pad 266
    int img = bid >> 6, h = bid & 63;
    const float* xp = x + (size_t)img * CIN * HWSZ + h * 64;
    int w = tid & 63, cq = tid >> 6;
    for (int cb = 0; cb < 256; cb += 4) {
      int c = cb + cq;
      T[w * 266 + c] = f2bf(xp[(size_t)c * HWSZ + w]);   // lanes=w: coalesced
    }
    __syncthreads();
    int w2 = tid >> 2, cg = (tid & 3) << 6;
    unsigned short* o = xt + ((size_t)(img * 64 + h) * 64 + w2) * 256 + cg;
#pragma unroll
    for (int i = 0; i < 64; i += 8) {
      short8 v = *(short8*)&T[w2 * 266 + cg + i];
      *(short8*)(o + i) = v;
    }
  } else if (bid < 544) {
    // Bfrag: e in [0, 73728): lane=e&63, nt=(e>>6)&7, s16=e>>9
    int e = (bid - 256) * 256 + tid;
    int lane = e & 63, nt = (e >> 6) & 7, s16 = e >> 9;
    int n = nt * 32 + (lane & 31);
    int kb = s16 * 16 + ((lane >> 5) << 3);
    short8 pk;
#pragma unroll
    for (int j = 0; j < 8; ++j) {
      int k = kb + j;
      pk[j] = (short)f2bf(dcn_w[n * KTOT + (k & 255) * 9 + (k >> 8)]);
    }
    *(short8*)(Bfrag + (size_t)e * 8) = pk;
  } else {
    // B2frag: e in [0, 9216): lane=e&63, nt=(e>>6)&1, s32=e>>7
    int e = (bid - 544) * 256 + tid;
    int lane = e & 63, nt = (e >> 6) & 1, s32 = e >> 7;
    int n = nt * 16 + (lane & 15);
    int kb = s32 * 32 + ((lane >> 4) << 3);
    short8 pk;
#pragma unroll
    for (int j = 0; j < 8; ++j) {
      int k = kb + j;
      pk[j] = (n < 27) ? (short)f2bf(offw[n * KTOT + (k & 255) * 9 + (k >> 8)])
                       : (short)0;
    }
    *(short8*)(B2frag + (size_t)e * 8) = pk;
  }
}

// ---------------------------------------------------------------------------
// Kernel 1 (main): FULLY FUSED offset-conv + sampling + GEMM, v6.
// Identical to v5 except the per-step barrier is lgkmcnt-only (raw s_barrier)
// so the B-frag (s+1) and corner (s+2) global prefetches stay in flight
// across it — the compiler's fine-grained vmcnt waits gate their register
// consumption instead of a full drain.
// ---------------------------------------------------------------------------
__global__ __launch_bounds__(512, 2) void dcn_fused_kernel(
    const unsigned short* __restrict__ xt,
    const unsigned short* __restrict__ Bfrag,
    const unsigned short* __restrict__ B2frag,
    const float* __restrict__ ob, float* __restrict__ out) {
  __shared__ unsigned short Ald[2][520 * 8];    // 16.6 KB padded-granule dbuf
  __shared__ intx4  sOff[576];                  //  9 KB
  __shared__ float4 sWt[576];                   //  9 KB
  __shared__ float  omp[4 * 32 * 68];           // 34.8 KB conv partials

  int bid = blockIdx.x;                 // 0..255 = (img,h)
  int img = bid >> 6, h = bid & 63;
  const unsigned short* xb = xt + (size_t)img * HWSZ * 256;

  int tid  = threadIdx.x;
  int lane = tid & 63, q = tid >> 6;    // 8 waves
  int quad = lane >> 4, l15 = lane & 15;
  int l31  = lane & 31,  lh5 = lane >> 5;

  // ================= Phase A: offset conv (waves 0-3, K-split) =============
  if (q < 4) {
    floatx4 cacc[4][2];
#pragma unroll
    for (int mt = 0; mt < 4; ++mt)
#pragma unroll
      for (int nt = 0; nt < 2; ++nt) cacc[mt][nt] = (floatx4){0.f, 0.f, 0.f, 0.f};
    short8 cpa[2][4];
    short8 cpb[2][2];

#define CONV_LOAD(I, SLOT)                                                     \
  {                                                                            \
    int s = q + (I) * 4;                                                       \
    int t = s >> 3;                                                            \
    int dy = t / 3 - 1, dx = t % 3 - 1;                                        \
    int y = h + dy;                                                            \
    int cb0 = ((s & 7) << 5) + (quad << 3);                                    \
    _Pragma("unroll")                                                          \
    for (int mt = 0; mt < 4; ++mt) {                                           \
      int xx = mt * 16 + l15 + dx;                                             \
      short8 v = {0, 0, 0, 0, 0, 0, 0, 0};                                     \
      if (((unsigned)y < 64u) && ((unsigned)xx < 64u))                         \
        v = *(const short8*)(xb + ((y * 64 + xx) << 8) + cb0);                 \
      cpa[SLOT][mt] = v;                                                       \
    }                                                                          \
    _Pragma("unroll")                                                          \
    for (int nt = 0; nt < 2; ++nt)                                             \
      cpb[SLOT][nt] = *(const short8*)(B2frag + (((s * 2 + nt) * 64 + lane) << 3)); \
  }

    CONV_LOAD(0, 0);
#pragma unroll 2
    for (int i = 0; i < 18; ++i) {
      int sl = i & 1;
      if (i < 17) CONV_LOAD(i + 1, sl ^ 1);
#pragma unroll
      for (int mt = 0; mt < 4; ++mt)
#pragma unroll
        for (int nt = 0; nt < 2; ++nt)
          cacc[mt][nt] = __builtin_amdgcn_mfma_f32_16x16x32_bf16(
              cpa[sl][mt], cpb[sl][nt], cacc[mt][nt], 0, 0, 0);
    }
#undef CONV_LOAD
#pragma unroll
    for (int mt = 0; mt < 4; ++mt)
#pragma unroll
      for (int nt = 0; nt < 2; ++nt) {
        int oc = nt * 16 + l15;
        float4 vv = make_float4(cacc[mt][nt][0], cacc[mt][nt][1],
                                cacc[mt][nt][2], cacc[mt][nt][3]);
        *(float4*)&omp[(q * 32 + oc) * 68 + mt * 16 + quad * 4] = vv;
      }
  }
  __syncthreads();

  // ---- bilinear params: 9 taps x 64 w (sum 4 K-partials + bias) ----
  for (int v = tid; v < 576; v += 512) {
    int w = v & 63, t = v >> 6;
    int ky = t / 3, kx = t % 3;
    float offy = omp[(0 * 32 + 2 * t) * 68 + w] + omp[(1 * 32 + 2 * t) * 68 + w] +
                 omp[(2 * 32 + 2 * t) * 68 + w] + omp[(3 * 32 + 2 * t) * 68 + w] +
                 ob[2 * t];
    float offx = omp[(0 * 32 + 2 * t + 1) * 68 + w] + omp[(1 * 32 + 2 * t + 1) * 68 + w] +
                 omp[(2 * 32 + 2 * t + 1) * 68 + w] + omp[(3 * 32 + 2 * t + 1) * 68 + w] +
                 ob[2 * t + 1];
    float mraw = omp[(0 * 32 + 18 + t) * 68 + w] + omp[(1 * 32 + 18 + t) * 68 + w] +
                 omp[(2 * 32 + 18 + t) * 68 + w] + omp[(3 * 32 + 18 + t) * 68 + w] +
                 ob[18 + t];
    float mv   = 1.0f / (1.0f + __expf(-mraw));
    float him  = (float)(h - 1 + ky) + offy;
    float wim  = (float)(w - 1 + kx) + offx;
    float y0f = floorf(him), x0f = floorf(wim);
    float lhf = him - y0f, lwf = wim - x0f;
    int y0 = (int)y0f, x0i = (int)x0f;
    bool vy0 = (y0 >= 0) && (y0 < HH);
    bool vy1 = (y0 + 1 >= 0) && (y0 + 1 < HH);
    bool vx0 = (x0i >= 0) && (x0i < WW);
    bool vx1 = (x0i + 1 >= 0) && (x0i + 1 < WW);
    float hh_ = 1.0f - lhf, hw_ = 1.0f - lwf;
    float4 wt;
    wt.x = (vy0 && vx0) ? hh_ * hw_ * mv : 0.0f;
    wt.y = (vy0 && vx1) ? hh_ * lwf * mv : 0.0f;
    wt.z = (vy1 && vx0) ? lhf * hw_ * mv : 0.0f;
    wt.w = (vy1 && vx1) ? lhf * lwf * mv : 0.0f;
    int y0c = min(max(y0, 0), 63), y1c = min(max(y0 + 1, 0), 63);
    int x0c = min(max(x0i, 0), 63), x1c = min(max(x0i + 1, 0), 63);
    intx4 ii = {(y0c * 64 + x0c) << 8, (y0c * 64 + x1c) << 8,
                (y1c * 64 + x0c) << 8, (y1c * 64 + x1c) << 8};
    sOff[v] = ii;
    sWt[v]  = wt;
  }

  // ================= Phase B: fused sampling + GEMM ========================
  floatx16 acc[2];
#pragma unroll
  for (int mt = 0; mt < 2; ++mt)
#pragma unroll
    for (int e = 0; e < 16; ++e) acc[mt][e] = 0.f;

  int sm  = tid >> 3;          // sampler m row (0..63)
  int chk = tid & 7;           // 8-c chunk within K64 window
  // write granule: blk = sub*2 + mt, row = (chk&1)*32 + (m&31)
  int wgran = (((chk >> 1) << 1) + (sm >> 5)) * 65 + ((chk & 1) << 5) + (sm & 31);

  short8 bfr[2][4];            // B frags ping-pong [s&1][sub]
  short8 cr[4];                // corner regs
  float4 pwt;

  __syncthreads();             // params ready (full sync once)

  // ---- prologue ----
#pragma unroll
  for (int sub = 0; sub < 4; ++sub)
    bfr[0][sub] = *(const short8*)(
        Bfrag + (((size_t)sub * 8 + q) * 64 + lane) * 8);
  {
    intx4 off = sOff[sm];
    float4 w0 = sWt[sm];
    int cb = chk * 8;          // s=0: t=0, cq=0
    cr[0] = *(const short8*)(xb + off.x + cb);
    cr[1] = *(const short8*)(xb + off.y + cb);
    cr[2] = *(const short8*)(xb + off.z + cb);
    cr[3] = *(const short8*)(xb + off.w + cb);
    short8 pk;
#pragma unroll
    for (int j = 0; j < 8; ++j) {
      float v = w0.x * b2f((unsigned short)cr[0][j]) +
                w0.y * b2f((unsigned short)cr[1][j]) +
                w0.z * b2f((unsigned short)cr[2][j]) +
                w0.w * b2f((unsigned short)cr[3][j]);
      pk[j] = (short)f2bf(v);
    }
    *(short8*)&Ald[0][wgran * 8] = pk;
  }
  {
    // corners for s=1 (t=0, cq=1)
    intx4 off = sOff[sm];
    pwt = sWt[sm];
    int cb = 64 + chk * 8;
    cr[0] = *(const short8*)(xb + off.x + cb);
    cr[1] = *(const short8*)(xb + off.y + cb);
    cr[2] = *(const short8*)(xb + off.z + cb);
    cr[3] = *(const short8*)(xb + off.w + cb);
  }
  __syncthreads();             // buf0 ready (full sync once; corners(1) ride)

  // ---- main loop: 36 K64-steps, lgkm-only barrier ----
#pragma unroll 2
  for (int s = 0; s < 36; ++s) {
    int cur = s & 1;
    if (s < 35) {
      // B frags for s+1 (register loads, dup-free: wave q owns nt=q)
      int s16b = (s + 1) * 4;
#pragma unroll
      for (int sub = 0; sub < 4; ++sub)
        bfr[cur ^ 1][sub] = *(const short8*)(
            Bfrag + (((size_t)(s16b + sub) * 8 + q) * 64 + lane) * 8);
      // pack corners(s+1) -> Ald[cur^1]
      short8 pk;
#pragma unroll
      for (int j = 0; j < 8; ++j) {
        float v = pwt.x * b2f((unsigned short)cr[0][j]) +
                  pwt.y * b2f((unsigned short)cr[1][j]) +
                  pwt.z * b2f((unsigned short)cr[2][j]) +
                  pwt.w * b2f((unsigned short)cr[3][j]);
        pk[j] = (short)f2bf(v);
      }
      *(short8*)&Ald[cur ^ 1][wgran * 8] = pk;
    }
    if (s < 34) {
      // corner loads for s+2 (stay in flight across the barrier)
      int s2 = s + 2;
      int t2 = s2 >> 2;
      intx4 off = sOff[t2 * 64 + sm];
      pwt = sWt[t2 * 64 + sm];
      int cb = (s2 & 3) * 64 + chk * 8;
      cr[0] = *(const short8*)(xb + off.x + cb);
      cr[1] = *(const short8*)(xb + off.y + cb);
      cr[2] = *(const short8*)(xb + off.z + cb);
      cr[3] = *(const short8*)(xb + off.w + cb);
    }
    // 8 MFMA (32x32x16): a from padded-granule LDS, b from regs
#pragma unroll
    for (int sub = 0; sub < 4; ++sub) {
      short8 a0 = *(short8*)&Ald[cur][((sub * 2 + 0) * 65 + lane) * 8];
      short8 a1 = *(short8*)&Ald[cur][((sub * 2 + 1) * 65 + lane) * 8];
      acc[0] = __builtin_amdgcn_mfma_f32_32x32x16_bf16(
          a0, bfr[cur][sub], acc[0], 0, 0, 0);
      acc[1] = __builtin_amdgcn_mfma_f32_32x32x16_bf16(
          a1, bfr[cur][sub], acc[1], 0, 0, 0);
    }
    barrier_lds_only();   // orders LDS dbuf only — vm prefetches stay in flight
  }

  // ---- epilogue: D col = oc (lane&31), row = (r&3)+8*(r>>2)+4*(lane>>5) ----
  int oc = q * 32 + l31;
#pragma unroll
  for (int mt = 0; mt < 2; ++mt) {
    float* obase = out + (((size_t)img * OUTC + oc) << 12) + h * 64 +
                   mt * 32 + lh5 * 4;
#pragma unroll
    for (int rg = 0; rg < 4; ++rg) {
      float4 vv = make_float4(acc[mt][rg * 4 + 0], acc[mt][rg * 4 + 1],
                              acc[mt][rg * 4 + 2], acc[mt][rg * 4 + 3]);
      *(float4*)(obase + rg * 8) = vv;
    }
  }
}

// ===========================================================================
// FALLBACK PATH (round-2 kernels) — only if ws is too small (< ~9.7 MB).
// ===========================================================================
__global__ __launch_bounds__(256) void prep_fb_kernel(
    const float* __restrict__ dcn_w, const float* __restrict__ offw,
    unsigned short* __restrict__ Bw, unsigned short* __restrict__ B2w) {
  int oc = blockIdx.x;
  for (int k = threadIdx.x; k < KTOT; k += 256) {
    int t = k >> 8, c = k & 255;
    Bw[oc * KTOT + k] = f2bf(dcn_w[oc * KTOT + c * 9 + t]);
    if (oc < 32)
      B2w[oc * KTOT + k] = (oc < 27) ? f2bf(offw[oc * KTOT + c * 9 + t])
                                     : (unsigned short)0;
  }
}

__global__ __launch_bounds__(256) void conv_offset_kernel(
    const float* __restrict__ x, const unsigned short* __restrict__ B2w,
    const float* __restrict__ ob, float* __restrict__ om) {
  __shared__ unsigned short A_lds[64 * 40];
  __shared__ unsigned short B_lds[32 * 40];
  int bid = blockIdx.x;
  int n = bid >> 6, h = bid & 63;
  int tid = threadIdx.x, lane = tid & 63, q = tid >> 6;
  const float* xn = x + n * (CIN * HWSZ);
  floatx4 acc0 = {0.f, 0.f, 0.f, 0.f}, acc1 = {0.f, 0.f, 0.f, 0.f};
  int w = tid & 63, cg = tid >> 6, ocb = tid >> 3, part = tid & 7;
  for (int s = 0; s < NSTEPS; ++s) {
    int t = s >> 3, c0 = (s & 7) << 5;
    int dy = t / 3 - 1, dx = t % 3 - 1;
    __syncthreads();
    {
      int y = h + dy, xx = w + dx;
      bool inb = ((unsigned)y < 64u) && ((unsigned)xx < 64u);
      const float* xb = xn + (c0 + cg * 8) * HWSZ + y * 64 + xx;
      short8 pk;
#pragma unroll
      for (int j = 0; j < 8; ++j) { float v = inb ? xb[j * HWSZ] : 0.0f; pk[j] = (short)f2bf(v); }
      *(short8*)&A_lds[w * 40 + cg * 8] = pk;
    }
    { const unsigned short* bp = B2w + ocb * KTOT + (t << 8) + c0 + part * 4;
      *(short4v*)&B_lds[ocb * 40 + part * 4] = *(const short4v*)bp; }
    __syncthreads();
    int fr = (lane >> 4) * 8;
    short8 af  = *(short8*)&A_lds[(q * 16 + (lane & 15)) * 40 + fr];
    short8 bf0 = *(short8*)&B_lds[((lane & 15)) * 40 + fr];
    short8 bf1 = *(short8*)&B_lds[(16 + (lane & 15)) * 40 + fr];
    acc0 = __builtin_amdgcn_mfma_f32_16x16x32_bf16(af, bf0, acc0, 0, 0, 0);
    acc1 = __builtin_amdgcn_mfma_f32_16x16x32_bf16(af, bf1, acc1, 0, 0, 0);
  }
  int g = lane >> 4;
#pragma unroll
  for (int nt = 0; nt < 2; ++nt) {
    floatx4 a = nt ? acc1 : acc0;
    int oc = nt * 16 + (lane & 15);
    if (oc < 27) {
      float bias = ob[oc];
#pragma unroll
      for (int r = 0; r < 4; ++r) {
        int wm = q * 16 + g * 4 + r;
        float val = a[r] + bias;
        if (oc >= 18) val = 1.0f / (1.0f + __expf(-val));
        om[((n * 27 + oc) << 12) + h * 64 + wm] = val;
      }
    }
  }
}

__global__ __launch_bounds__(256) void dcn_main_kernel(
    const float* __restrict__ x, const float* __restrict__ om,
    const unsigned short* __restrict__ Bw, float* __restrict__ out) {
  __shared__ unsigned short A_lds[32 * 40];
  __shared__ unsigned short B_lds[256 * 40];
  __shared__ int    sY[288];
  __shared__ int    sX[288];
  __shared__ float4 sW[288];
  int bid = blockIdx.x;
  int n = bid >> 7, rem = bid & 127, h = rem >> 1, w0 = (rem & 1) << 5;
  int tid = threadIdx.x, lane = tid & 63, q = tid >> 6;
  const float* xn  = x + n * (CIN * HWSZ);
  const float* omn = om + n * (27 * HWSZ);
  for (int v = tid; v < 288; v += 256) {
    int m = v & 31, t = v >> 5;
    int ky = t / 3, kx = t % 3;
    int wg = w0 + m, sp = h * 64 + wg;
    float offy = omn[(2 * t) * HWSZ + sp];
    float offx = omn[(2 * t + 1) * HWSZ + sp];
    float mv   = omn[(18 + t) * HWSZ + sp];
    float him = (float)(h - 1 + ky) + offy;
    float wim = (float)(wg - 1 + kx) + offx;
    float y0f = floorf(him), x0f = floorf(wim);
    float lh = him - y0f, lw = wim - x0f;
    int y0 = (int)y0f, x0i = (int)x0f;
    bool vy0 = (y0 >= 0) && (y0 < HH), vy1 = (y0 + 1 >= 0) && (y0 + 1 < HH);
    bool vx0 = (x0i >= 0) && (x0i < WW), vx1 = (x0i + 1 >= 0) && (x0i + 1 < WW);
    float hh_ = 1.0f - lh, hw_ = 1.0f - lw;
    float4 wt;
    wt.x = (vy0 && vx0) ? hh_ * hw_ * mv : 0.0f;
    wt.y = (vy0 && vx1) ? hh_ * lw  * mv : 0.0f;
    wt.z = (vy1 && vx0) ? lh  * hw_ * mv : 0.0f;
    wt.w = (vy1 && vx1) ? lh  * lw  * mv : 0.0f;
    sY[v] = y0; sX[v] = x0i; sW[v] = wt;
  }
  floatx4 acc[2][4];
#pragma unroll
  for (int mi = 0; mi < 2; ++mi)
#pragma unroll
    for (int nj = 0; nj < 4; ++nj) acc[mi][nj] = (floatx4){0.f, 0.f, 0.f, 0.f};
  int m = tid & 31, cg = tid >> 5, n0 = q * 64;
  for (int s = 0; s < NSTEPS; ++s) {
    int t = s >> 3, c0 = (s & 7) << 5;
    __syncthreads();
    {
      int p = t * 32 + m;
      int y0 = sY[p], x0i = sX[p];
      float4 wt = sW[p];
      int y0c = min(max(y0, 0), 63), y1c = min(max(y0 + 1, 0), 63);
      int x0c = min(max(x0i, 0), 63), x1c = min(max(x0i + 1, 0), 63);
      int i00 = y0c * 64 + x0c, i01 = y0c * 64 + x1c;
      int i10 = y1c * 64 + x0c, i11 = y1c * 64 + x1c;
      const float* xb = xn + (c0 + cg * 4) * HWSZ;
      short4v pk;
#pragma unroll
      for (int j = 0; j < 4; ++j) {
        const float* xc = xb + j * HWSZ;
        float v = wt.x * xc[i00] + wt.y * xc[i01] + wt.z * xc[i10] + wt.w * xc[i11];
        pk[j] = (short)f2bf(v);
      }
      *(short4v*)&A_lds[m * 40 + cg * 4] = pk;
    }
    {
      const short8* bp = (const short8*)(Bw + tid * KTOT + (t << 8) + c0);
      short8 b0 = bp[0], b1 = bp[1], b2 = bp[2], b3 = bp[3];
      short8* dst = (short8*)&B_lds[tid * 40];
      dst[0] = b0; dst[1] = b1; dst[2] = b2; dst[3] = b3;
    }
    __syncthreads();
    int fr = (lane >> 4) * 8;
    short8 a0 = *(short8*)&A_lds[((lane & 15)) * 40 + fr];
    short8 a1 = *(short8*)&A_lds[(16 + (lane & 15)) * 40 + fr];
#pragma unroll
    for (int nj = 0; nj < 4; ++nj) {
      short8 bfp = *(short8*)&B_lds[(n0 + nj * 16 + (lane & 15)) * 40 + fr];
      acc[0][nj] = __builtin_amdgcn_mfma_f32_16x16x32_bf16(a0, bfp, acc[0][nj], 0, 0, 0);
      acc[1][nj] = __builtin_amdgcn_mfma_f32_16x16x32_bf16(a1, bfp, acc[1][nj], 0, 0, 0);
    }
  }
  int g = lane >> 4;
#pragma unroll
  for (int mi = 0; mi < 2; ++mi) {
    int wm = w0 + mi * 16 + g * 4;
#pragma unroll
    for (int nj = 0; nj < 4; ++nj) {
      int oc = n0 + nj * 16 + (lane & 15);
      float4 vv = make_float4(acc[mi][nj][0], acc[mi][nj][1],
                              acc[mi][nj][2], acc[mi][nj][3]);
      *(float4*)&out[((n * OUTC + oc) << 12) + h * 64 + wm] = vv;
    }
  }
}

// ---------------------------------------------------------------------------
extern "C" void kernel_launch(void* const* d_in, const int* in_sizes, int n_in,
                              void* d_out, int out_size, void* d_ws, size_t ws_size,
                              hipStream_t stream) {
  const float* x     = (const float*)d_in[0];
  const float* offw  = (const float*)d_in[1];
  const float* ob    = (const float*)d_in[2];
  const float* dcn_w = (const float*)d_in[3];
  float* out = (float*)d_out;

  if (ws_size >= (size_t)WSM_END) {
    unsigned short* Bfrag  = (unsigned short*)((char*)d_ws + WSM_BFRAG);
    unsigned short* B2frag = (unsigned short*)((char*)d_ws + WSM_B2FRAG);
    unsigned short* xtb    = (unsigned short*)((char*)d_ws + WSM_XT);
    // main path: 2 launches total
    prep_main_kernel<<<580, 256, 0, stream>>>(dcn_w, offw, x, Bfrag, B2frag, xtb);
    dcn_fused_kernel<<<256, 512, 0, stream>>>(xtb, Bfrag, B2frag, ob, out);
  } else {
    unsigned short* Bw  = (unsigned short*)((char*)d_ws + WSF_BW);
    unsigned short* B2w = (unsigned short*)((char*)d_ws + WSF_B2W);
    float*          omb = (float*)((char*)d_ws + WSF_OM);
    prep_fb_kernel<<<256, 256, 0, stream>>>(dcn_w, offw, Bw, B2w);
    conv_offset_kernel<<<NB * HH, 256, 0, stream>>>(x, B2w, ob, omb);
    dcn_main_kernel<<<NB * HH * 2, 256, 0, stream>>>(x, omb, Bw, out);
  }
}